// Round 3
// baseline (1172.576 us; speedup 1.0000x reference)
//
#include <hip/hip_runtime.h>
#include <stdint.h>

#define LSEQ 64
#define BATCH 2048
#define HID 512
#define NG 2048          // 4*HID gate rows (permuted: n = 4*j + q)
#define KP 576           // 512 + 64 (E=50 padded to 64)
#define VOCAB 96
#define BH (BATCH*HID)   // 1048576

typedef unsigned short u16;
typedef __attribute__((ext_vector_type(8))) short short8;
typedef __attribute__((ext_vector_type(4))) float f32x4;

__device__ __forceinline__ u16 f2bf(float f) {
    union { float f; unsigned u; } v; v.f = f;
    return (u16)((v.u + 0x7FFFu + ((v.u >> 16) & 1u)) >> 16);   // RNE
}
__device__ __forceinline__ float sig_(float x) { return 1.f / (1.f + __expf(-x)); }
__device__ __forceinline__ float th_(float x) {
    x = fminf(fmaxf(x, -30.f), 30.f);
    float e = __expf(2.f * x);
    return (e - 1.f) / (e + 1.f);
}
__device__ __forceinline__ void gld16(const void* g, void* l) {
    __builtin_amdgcn_global_load_lds(
        (const __attribute__((address_space(1))) unsigned int*)g,
        (__attribute__((address_space(3))) unsigned int*)l, 16, 0, 0);
}

// ---------------- prep kernels ----------------
__global__ void k_init(const float* __restrict__ h0, const float* __restrict__ c0,
                       u16* __restrict__ hs0, float* __restrict__ cws) {
    int i = blockIdx.x * 256 + threadIdx.x;       // BH threads exactly
    hs0[i] = f2bf(h0[i]);
    cws[i] = c0[i];
}

// Wp[n][k], n = 4*j+q -> src row q*512+j of [W_hh | W_ih | pad]; bias fused.
__global__ void k_pack_w(const float* __restrict__ Wih, const float* __restrict__ Whh,
                         const float* __restrict__ bih, const float* __restrict__ bhh,
                         u16* __restrict__ Wp, float* __restrict__ bp) {
    int id = blockIdx.x * 256 + threadIdx.x;      // NG*72 threads exactly
    int n = id / 72, kc = id % 72;
    int j = n >> 2, q = n & 3;
    int src = q * HID + j;
    int k0 = kc * 8;
    unsigned pk[4];
#pragma unroll
    for (int t = 0; t < 4; ++t) {
        int k = k0 + 2 * t;
        float f0 = (k < 512) ? Whh[src * 512 + k] : ((k < 562) ? Wih[src * 50 + k - 512] : 0.f);
        float f1 = (k + 1 < 512) ? Whh[src * 512 + k + 1]
                                 : ((k + 1 < 562) ? Wih[src * 50 + k + 1 - 512] : 0.f);
        pk[t] = (unsigned)f2bf(f0) | ((unsigned)f2bf(f1) << 16);
    }
    *(uint4*)(Wp + (size_t)n * KP + k0) = make_uint4(pk[0], pk[1], pk[2], pk[3]);
    if (kc == 0) bp[n] = bih[src] + bhh[src];
}

// x_bf16[l*B + b][64]: emb[ids[l,b], 0:50], zero-padded to 64
__global__ void k_embed(const int* __restrict__ ids, const float* __restrict__ emb,
                        u16* __restrict__ xb) {
    int id = blockIdx.x * 256 + threadIdx.x;      // LSEQ*BATCH*8 threads exactly
    int row = id >> 3, kc = id & 7;
    int tok = ids[row];
    int k0 = kc * 8;
    unsigned pk[4];
#pragma unroll
    for (int t = 0; t < 4; ++t) {
        int k = k0 + 2 * t;
        unsigned lo = (k < 50) ? (unsigned)f2bf(emb[tok * 50 + k]) : 0u;
        unsigned hi = (k + 1 < 50) ? (unsigned)f2bf(emb[tok * 50 + k + 1]) : 0u;
        pk[t] = lo | (hi << 16);
    }
    *(uint4*)(xb + (size_t)row * 64 + k0) = make_uint4(pk[0], pk[1], pk[2], pk[3]);
}

__global__ void k_pack_wout(const float* __restrict__ Wo, u16* __restrict__ Wb) {
    int id = blockIdx.x * 256 + threadIdx.x;      // VOCAB*HID/8 = 6144 threads
    int k0 = id * 8;
    unsigned pk[4];
#pragma unroll
    for (int t = 0; t < 4; ++t)
        pk[t] = (unsigned)f2bf(Wo[k0 + 2 * t]) | ((unsigned)f2bf(Wo[k0 + 2 * t + 1]) << 16);
    *(uint4*)(Wb + k0) = make_uint4(pk[0], pk[1], pk[2], pk[3]);
}

// ---------------- fused gate-GEMM + LSTM cell, one timestep ----------------
// grid (16,16): block = 128 batch rows x 128 permuted gate cols; 256 thr = 4 waves (2x2)
__global__ __launch_bounds__(256) void k_step(
    const u16* __restrict__ hprev, u16* __restrict__ hnext,
    const u16* __restrict__ xl, const u16* __restrict__ Wp,
    const float* __restrict__ bp, float* __restrict__ cws,
    float* __restrict__ outH, float* __restrict__ outC)
{
    __shared__ char smem[65536];
    u16* As = (u16*)smem;               // [128][64] bf16
    u16* Bs = (u16*)(smem + 16384);     // [128][64] bf16
    float* gsm = (float*)smem;          // [128][128] f32 (epilogue reuse)

    const int tid = threadIdx.x;
    const int lane = tid & 63;
    const int w = tid >> 6;
    const int wm = w >> 1, wn = w & 1;
    const int m0 = blockIdx.x * 128;
    const int n0 = blockIdx.y * 128;
    const int colo = (lane & 7) * 8;
    const int rsub = lane >> 3;

    f32x4 acc[4][4] = {};

    for (int kt = 0; kt < 9; ++kt) {
        const u16* baseA;
        int strideA, kofs;
        if (kt < 8) { baseA = hprev; strideA = 512; kofs = kt * 64; }
        else        { baseA = xl;    strideA = 64;  kofs = 0; }
#pragma unroll
        for (int it = 0; it < 4; ++it) {
            int wc = w * 4 + it;                  // wave-uniform chunk id 0..15
            int r = wc * 8 + rsub;                // tile row 0..127
            gld16(baseA + (size_t)(m0 + r) * strideA + kofs + colo, smem + wc * 1024);
            gld16(Wp + (size_t)(n0 + r) * KP + kt * 64 + colo, smem + 16384 + wc * 1024);
        }
        __syncthreads();
#pragma unroll
        for (int kk = 0; kk < 2; ++kk) {
            short8 av[4], bv[4];
#pragma unroll
            for (int i = 0; i < 4; ++i) {
                av[i] = *(const short8*)(As + (wm * 64 + i * 16 + (lane & 15)) * 64 + kk * 32 + (lane >> 4) * 8);
                bv[i] = *(const short8*)(Bs + (wn * 64 + i * 16 + (lane & 15)) * 64 + kk * 32 + (lane >> 4) * 8);
            }
#pragma unroll
            for (int i = 0; i < 4; ++i)
#pragma unroll
                for (int j = 0; j < 4; ++j)
                    acc[i][j] = __builtin_amdgcn_mfma_f32_16x16x32_bf16(av[i], bv[j], acc[i][j], 0, 0, 0);
        }
        __syncthreads();
    }

    // acc -> LDS gates[128][128] (f32), D layout: col=lane&15, row=4*(lane>>4)+r
#pragma unroll
    for (int i = 0; i < 4; ++i) {
        int ml = wm * 64 + i * 16 + (lane >> 4) * 4;
#pragma unroll
        for (int j = 0; j < 4; ++j) {
            int nl = wn * 64 + j * 16 + (lane & 15);
#pragma unroll
            for (int r = 0; r < 4; ++r)
                gsm[(ml + r) * 128 + nl] = acc[i][j][r];
        }
    }
    __syncthreads();

    // LSTM cell: 128 b-rows x 32 j-cols per block, 16 cells/thread
    const float* bpn = bp + n0;
#pragma unroll
    for (int p = 0; p < 16; ++p) {
        int idx = p * 256 + tid;
        int bl = idx >> 5;                 // 0..127
        int jl = idx & 31;                 // 0..31
        float4 g = *(const float4*)(gsm + bl * 128 + jl * 4);
        float4 bb = *(const float4*)(bpn + jl * 4);
        float gi = g.x + bb.x, gf = g.y + bb.y, gg = g.z + bb.z, go = g.w + bb.w;
        size_t ci = (size_t)(m0 + bl) * HID + (n0 >> 2) + jl;
        float c_old = cws[ci];
        float cn = sig_(gf) * c_old + sig_(gi) * th_(gg);
        float hn = sig_(go) * th_(cn);
        cws[ci] = cn;
        hnext[ci] = f2bf(hn);
        if (outH) { outH[ci] = hn; outC[ci] = cn; }   // f32 outputs (ref dtype)
    }
}

// ---------------- output projection: (L*B, 512) x (96, 512)^T ----------------
__global__ __launch_bounds__(256) void k_scores(
    const u16* __restrict__ hsall, const u16* __restrict__ Wb,
    const float* __restrict__ bo, float* __restrict__ out)
{
    __shared__ char smem[28672];
    u16* As = (u16*)smem;               // [128][64]
    u16* Bs = (u16*)(smem + 16384);     // [96][64]
    const int tid = threadIdx.x, lane = tid & 63, w = tid >> 6;
    const size_t m0 = (size_t)blockIdx.x * 128;
    const int colo = (lane & 7) * 8;
    const int rsub = lane >> 3;
    f32x4 acc[2][6] = {};

    for (int kt = 0; kt < 8; ++kt) {
#pragma unroll
        for (int it = 0; it < 4; ++it) {
            int wc = w * 4 + it;
            int r = wc * 8 + rsub;
            gld16(hsall + (m0 + r) * 512 + kt * 64 + colo, smem + wc * 1024);
        }
#pragma unroll
        for (int it = 0; it < 3; ++it) {
            int wc = w * 3 + it;                  // 0..11
            int r = wc * 8 + rsub;                // 0..95
            gld16(Wb + (size_t)r * 512 + kt * 64 + colo, smem + 16384 + wc * 1024);
        }
        __syncthreads();
#pragma unroll
        for (int kk = 0; kk < 2; ++kk) {
            short8 av[2], bv[6];
#pragma unroll
            for (int i = 0; i < 2; ++i)
                av[i] = *(const short8*)(As + (w * 32 + i * 16 + (lane & 15)) * 64 + kk * 32 + (lane >> 4) * 8);
#pragma unroll
            for (int j = 0; j < 6; ++j)
                bv[j] = *(const short8*)(Bs + (j * 16 + (lane & 15)) * 64 + kk * 32 + (lane >> 4) * 8);
#pragma unroll
            for (int i = 0; i < 2; ++i)
#pragma unroll
                for (int j = 0; j < 6; ++j)
                    acc[i][j] = __builtin_amdgcn_mfma_f32_16x16x32_bf16(av[i], bv[j], acc[i][j], 0, 0, 0);
        }
        __syncthreads();   // next iteration's global_load_lds must not
                           // overwrite As/Bs while any wave still ds_reads tile kt
    }
#pragma unroll
    for (int i = 0; i < 2; ++i) {
        int ml = w * 32 + i * 16 + (lane >> 4) * 4;
#pragma unroll
        for (int j = 0; j < 6; ++j) {
            int v = j * 16 + (lane & 15);
            float bb = bo[v];
#pragma unroll
            for (int r = 0; r < 4; ++r)
                out[(m0 + ml + r) * 96 + v] = acc[i][j][r] + bb;   // f32 output
        }
    }
}

// ---------------- launcher ----------------
extern "C" void kernel_launch(void* const* d_in, const int* in_sizes, int n_in,
                              void* d_out, int out_size, void* d_ws, size_t ws_size,
                              hipStream_t stream) {
    const int*   ids  = (const int*)d_in[0];
    const float* h0   = (const float*)d_in[1];
    const float* c0   = (const float*)d_in[2];
    const float* emb  = (const float*)d_in[3];
    const float* Wih  = (const float*)d_in[4];
    const float* Whh  = (const float*)d_in[5];
    const float* bih  = (const float*)d_in[6];
    const float* bhh  = (const float*)d_in[7];
    const float* Wout = (const float*)d_in[8];
    const float* bout = (const float*)d_in[9];

    char* ws = (char*)d_ws;
    // ws layout (bytes):
    //   hs   : 65 * BH * 2              = 136,314,880
    //   cws  : BH * 4                   =   4,194,304
    //   xb   : L*B*64 * 2               =  16,777,216
    //   Wp   : 2048*576 * 2             =   2,359,296
    //   bp   : 2048 * 4                 =       8,192
    //   Wb   : 96*512 * 2               =      98,304
    u16*   hs  = (u16*)ws;
    float* cws = (float*)(ws + 136314880);
    u16*   xb  = (u16*)(ws + 140509184);
    u16*   Wp  = (u16*)(ws + 157286400);
    float* bp  = (float*)(ws + 159645696);
    u16*   Wb  = (u16*)(ws + 159653888);
    float* out = (float*)d_out;                       // reference output dtype = f32

    k_init<<<dim3(BH / 256), dim3(256), 0, stream>>>(h0, c0, hs, cws);
    k_pack_w<<<dim3(NG * 72 / 256), dim3(256), 0, stream>>>(Wih, Whh, bih, bhh, Wp, bp);
    k_embed<<<dim3(LSEQ * BATCH * 8 / 256), dim3(256), 0, stream>>>(ids, emb, xb);
    k_pack_wout<<<dim3(VOCAB * HID / 8 / 256), dim3(256), 0, stream>>>(Wout, Wb);

    for (int l = 0; l < LSEQ; ++l) {
        bool last = (l == LSEQ - 1);
        k_step<<<dim3(16, 16), dim3(256), 0, stream>>>(
            hs + (size_t)l * BH, hs + (size_t)(l + 1) * BH,
            xb + (size_t)l * BATCH * 64, Wp, bp, cws,
            last ? out + 12582912 : (float*)nullptr,
            last ? out + 12582912 + BH : (float*)nullptr);
    }

    k_scores<<<dim3(LSEQ * BATCH / 128), dim3(256), 0, stream>>>(hs + BH, Wb, bout, out);
}